// Round 9
// baseline (294.365 us; speedup 1.0000x reference)
//
#include <hip/hip_runtime.h>

#define HD 128

typedef __attribute__((ext_vector_type(8))) short short8;   // 8 bf16
typedef __attribute__((ext_vector_type(4))) float floatx4;  // MFMA accumulator

typedef unsigned short ushort_t;
typedef unsigned int uint_t;

// ---------------------------------------------------------------- helpers ----
__device__ __forceinline__ ushort_t f2b(float f) {          // fp32 -> bf16 RNE
    union { float f; uint_t u; } v; v.f = f;
    uint_t r = v.u + 0x7fff + ((v.u >> 16) & 1);
    return (ushort_t)(r >> 16);
}
__device__ __forceinline__ float b_lo(uint_t p) {
    union { uint_t u; float f; } v; v.u = p << 16; return v.f;
}
__device__ __forceinline__ float b_hi(uint_t p) {
    union { uint_t u; float f; } v; v.u = p & 0xffff0000u; return v.f;
}
__device__ __forceinline__ uint_t packb(float a, float b) { // both bf16-exact
    union { float f; uint_t u; } x, y; x.f = a; y.f = b;
    return (x.u >> 16) | (y.u & 0xffff0000u);
}
__device__ __forceinline__ short8 cvt8(const float* __restrict__ p) {
    float4 u = *(const float4*)p, v = *(const float4*)(p + 4);
    short8 r;
    r[0] = (short)f2b(u.x); r[1] = (short)f2b(u.y); r[2] = (short)f2b(u.z); r[3] = (short)f2b(u.w);
    r[4] = (short)f2b(v.x); r[5] = (short)f2b(v.y); r[6] = (short)f2b(v.z); r[7] = (short)f2b(v.w);
    return r;
}

// ------------------------------------------------------------------ prep -----
// [0,nbR): rowptr (rp[i] = lower_bound(dst,i)); rest: W-pack to frag order.
// Frag map (identical for A- and B-operand): lane&15 -> non-K dim, quad*8+j -> K.
__global__ __launch_bounds__(256) void k_prep(const int* __restrict__ dst, int E,
                                              int* __restrict__ rp, int N,
                                              const float* W0, const float* W1,
                                              const float* W2, const float* W3,
                                              const float* W4, const float* W5,
                                              ushort_t* __restrict__ Wpk, int nbR) {
    int b = blockIdx.x;
    if (b < nbR) {
        int i = b * 256 + threadIdx.x;
        if (i > N) return;
        int lo = 0, hi = E;
        while (lo < hi) {
            int mid = (lo + hi) >> 1;
            if (dst[mid] < i) lo = mid + 1; else hi = mid;
        }
        rp[i] = lo;
    } else {
        int bb = b - nbR;
        const float* Ws[6] = {W0, W1, W2, W3, W4, W5};
        int mat = bb >> 6;
        int o = ((bb & 63) << 8) + threadIdx.x;
        int j = o & 7, l = (o >> 3) & 63, s = (o >> 9) & 3, t = o >> 11;
        int k = s * 32 + ((l >> 4) & 3) * 8 + j;
        int n = t * 16 + (l & 15);
        Wpk[(size_t)mat * 16384 + o] = f2b(Ws[mat][k * HD + n]);
    }
}

// ---------------------------------------------------------- W -> LDS stage ---
__device__ __forceinline__ void stage_w(const ushort_t* __restrict__ g,
                                        ushort_t* l, int tid) {
#pragma unroll
    for (int i = 0; i < 8; ++i) {
        int off = i * 2048 + tid * 8;
        *(short8*)&l[off] = *(const short8*)&g[off];
    }
}

// --------------------------------------------------------------- epilogue ----
// D = mfma(Wfrag, hfrag): lane&15 = h-row, quad*4+reg = output col within tile.
__device__ __forceinline__ void store_bf16(ushort_t* __restrict__ m, int row,
                                           int colbase, const floatx4& acc,
                                           const float4& bv, bool relu, int N) {
    if (row >= N) return;
    float v0 = acc[0] + bv.x, v1 = acc[1] + bv.y, v2 = acc[2] + bv.z, v3 = acc[3] + bv.w;
    if (relu) { v0 = fmaxf(v0, 0.f); v1 = fmaxf(v1, 0.f); v2 = fmaxf(v2, 0.f); v3 = fmaxf(v3, 0.f); }
    uint2 o; o.x = (uint_t)f2b(v0) | ((uint_t)f2b(v1) << 16);
    o.y = (uint_t)f2b(v2) | ((uint_t)f2b(v3) << 16);
    *(uint2*)&m[(size_t)row * HD + colbase] = o;
}

// ------------------------------------------------------ gather + pool GEMM ---
// h0 = bf16(emb[ids]);  m = relu(h0 @ Wp + b).  A loads overlap W staging.
__global__ __launch_bounds__(256) void k_gather_pool(const int* __restrict__ ids,
                                                     const float* __restrict__ emb,
                                                     const ushort_t* __restrict__ Wpk,
                                                     const float* __restrict__ bias,
                                                     ushort_t* __restrict__ h0,
                                                     ushort_t* __restrict__ m, int N) {
    __shared__ ushort_t Wl[16384];
    int wave = blockIdx.x * 4 + (threadIdx.x >> 6);
    int row0 = wave * 32;
    int l = threadIdx.x & 63;
    int ar0 = row0 + (l & 15); if (ar0 >= N) ar0 = N - 1;
    int ar1 = ar0 + 16;        if (ar1 >= N) ar1 = N - 1;
    int ac = (l >> 4) * 8;
    int id0 = ids[ar0], id1 = ids[ar1];
    short8 a0[4], a1[4];
#pragma unroll
    for (int s = 0; s < 4; ++s) {
        a0[s] = cvt8(&emb[(size_t)id0 * HD + s * 32 + ac]);
        a1[s] = cvt8(&emb[(size_t)id1 * HD + s * 32 + ac]);
    }
    stage_w(Wpk, Wl, threadIdx.x);
    __syncthreads();
    if (row0 >= N) return;
#pragma unroll
    for (int s = 0; s < 4; ++s) {
        *(short8*)&h0[(size_t)ar0 * HD + s * 32 + ac] = a0[s];
        *(short8*)&h0[(size_t)ar1 * HD + s * 32 + ac] = a1[s];
    }
    int g0 = row0 + (l & 15), g1 = g0 + 16;
    int cb0 = ((l >> 4) & 3) * 4;
#pragma unroll
    for (int t = 0; t < 8; ++t) {
        floatx4 acc0 = {0.f, 0.f, 0.f, 0.f};
        floatx4 acc1 = {0.f, 0.f, 0.f, 0.f};
#pragma unroll
        for (int s = 0; s < 4; ++s) {
            short8 w = *(const short8*)&Wl[(t * 4 + s) * 512 + l * 8];
            acc0 = __builtin_amdgcn_mfma_f32_16x16x32_bf16(w, a0[s], acc0, 0, 0, 0);
            acc1 = __builtin_amdgcn_mfma_f32_16x16x32_bf16(w, a1[s], acc1, 0, 0, 0);
        }
        int cb = t * 16 + cb0;
        float4 bv = *(const float4*)&bias[cb];
        store_bf16(m, g0, cb, acc0, bv, true, N);
        store_bf16(m, g1, cb, acc1, bv, true, N);
    }
}

// ----------------------------------------------------------- pool GEMM only --
__global__ __launch_bounds__(256) void k_pool(const ushort_t* __restrict__ h,
                                              const ushort_t* __restrict__ Wpk,
                                              const float* __restrict__ bias,
                                              ushort_t* __restrict__ m, int N) {
    __shared__ ushort_t Wl[16384];
    int wave = blockIdx.x * 4 + (threadIdx.x >> 6);
    int row0 = wave * 32;
    int l = threadIdx.x & 63;
    int ar0 = row0 + (l & 15); if (ar0 >= N) ar0 = N - 1;
    int ar1 = ar0 + 16;        if (ar1 >= N) ar1 = N - 1;
    int ac = (l >> 4) * 8;
    short8 a0[4], a1[4];
#pragma unroll
    for (int s = 0; s < 4; ++s) {
        a0[s] = *(const short8*)&h[(size_t)ar0 * HD + s * 32 + ac];
        a1[s] = *(const short8*)&h[(size_t)ar1 * HD + s * 32 + ac];
    }
    stage_w(Wpk, Wl, threadIdx.x);
    __syncthreads();
    if (row0 >= N) return;
    int g0 = row0 + (l & 15), g1 = g0 + 16;
    int cb0 = ((l >> 4) & 3) * 4;
#pragma unroll
    for (int t = 0; t < 8; ++t) {
        floatx4 acc0 = {0.f, 0.f, 0.f, 0.f};
        floatx4 acc1 = {0.f, 0.f, 0.f, 0.f};
#pragma unroll
        for (int s = 0; s < 4; ++s) {
            short8 w = *(const short8*)&Wl[(t * 4 + s) * 512 + l * 8];
            acc0 = __builtin_amdgcn_mfma_f32_16x16x32_bf16(w, a0[s], acc0, 0, 0, 0);
            acc1 = __builtin_amdgcn_mfma_f32_16x16x32_bf16(w, a1[s], acc1, 0, 0, 0);
        }
        int cb = t * 16 + cb0;
        float4 bv = *(const float4*)&bias[cb];
        store_bf16(m, g0, cb, acc0, bv, true, N);
        store_bf16(m, g1, cb, acc1, bv, true, N);
    }
}

// ---------------------------------------------------------------- segmax -----
// Column-sliced, XCD-affine: blockIdx = group*4 + slice. With round-robin
// workgroup->XCD dispatch, slice j runs on XCDs {j, j+4}, so its 3.2 MB
// column slice of m stays resident in those XCDs' L2 (perf heuristic only —
// correctness does not depend on the mapping). One wave = one (node, slice);
// 8 edge-slots x 8 lanes x 8B = 64B per edge (one cache-line pair).
__global__ __launch_bounds__(256) void k_segmax(const ushort_t* __restrict__ m,
                                                const int* __restrict__ src,
                                                const int* __restrict__ rp,
                                                ushort_t* __restrict__ agg, int N) {
    int slice = blockIdx.x & 3;
    int node = (blockIdx.x >> 2) * 4 + (threadIdx.x >> 6);
    if (node >= N) return;
    int l = threadIdx.x & 63;
    int slot = l >> 3;                       // 0..7: edge slot
    int colbase = slice * 32 + (l & 7) * 4;  // 4 bf16 (8 B) per lane
    int beg = rp[node], end = rp[node + 1];
    float a0 = 0.f, a1 = 0.f, a2 = 0.f, a3 = 0.f;
    float c0 = 0.f, c1 = 0.f, c2 = 0.f, c3 = 0.f;
    for (int base = beg; base < end; base += 64) {
        int nb = end - base; if (nb > 64) nb = 64;
        int si = base + l; if (si > end - 1) si = end - 1;
        int sv = src[si];                    // coalesced: 64 edge indices
        for (int o = 0; o < nb; o += 16) {   // 16 edges in flight (2 loads/lane)
            int last = nb - 1;
            int i0 = o + slot;     if (i0 > last) i0 = last;
            int i1 = o + 8 + slot; if (i1 > last) i1 = last;
            int s0 = __shfl(sv, i0), s1 = __shfl(sv, i1);
            uint2 p0 = *(const uint2*)&m[(size_t)s0 * HD + colbase];
            uint2 p1 = *(const uint2*)&m[(size_t)s1 * HD + colbase];
            a0 = fmaxf(a0, b_lo(p0.x)); a1 = fmaxf(a1, b_hi(p0.x));
            a2 = fmaxf(a2, b_lo(p0.y)); a3 = fmaxf(a3, b_hi(p0.y));
            c0 = fmaxf(c0, b_lo(p1.x)); c1 = fmaxf(c1, b_hi(p1.x));
            c2 = fmaxf(c2, b_lo(p1.y)); c3 = fmaxf(c3, b_hi(p1.y));
        }
    }
    a0 = fmaxf(a0, c0); a1 = fmaxf(a1, c1); a2 = fmaxf(a2, c2); a3 = fmaxf(a3, c3);
    // merge the 8 slots (xor over slot bits: lane masks 8,16,32)
    a0 = fmaxf(a0, __shfl_xor(a0, 8));  a1 = fmaxf(a1, __shfl_xor(a1, 8));
    a2 = fmaxf(a2, __shfl_xor(a2, 8));  a3 = fmaxf(a3, __shfl_xor(a3, 8));
    a0 = fmaxf(a0, __shfl_xor(a0, 16)); a1 = fmaxf(a1, __shfl_xor(a1, 16));
    a2 = fmaxf(a2, __shfl_xor(a2, 16)); a3 = fmaxf(a3, __shfl_xor(a3, 16));
    a0 = fmaxf(a0, __shfl_xor(a0, 32)); a1 = fmaxf(a1, __shfl_xor(a1, 32));
    a2 = fmaxf(a2, __shfl_xor(a2, 32)); a3 = fmaxf(a3, __shfl_xor(a3, 32));
    if (slot == 0) {
        uint2 o; o.x = packb(a0, a1); o.y = packb(a2, a3);
        *(uint2*)&agg[(size_t)node * HD + colbase] = o;
    }
}

// ----------------------------------------------------------- dual GEMM -------
// out = h @ Wself + agg @ Wneigh + b; A/agg loads overlap W staging.
template <bool F32OUT>
__global__ __launch_bounds__(256) void k_dual(const ushort_t* __restrict__ h,
                                              const ushort_t* __restrict__ agg,
                                              const ushort_t* __restrict__ WsPk,
                                              const ushort_t* __restrict__ WnPk,
                                              const float* __restrict__ bias,
                                              void* __restrict__ outp, int N) {
    __shared__ ushort_t Wl[32768];                       // Ws | Wn
    int wave = blockIdx.x * 4 + (threadIdx.x >> 6);
    int row0 = wave * 32;
    int l = threadIdx.x & 63;
    int ar0 = row0 + (l & 15); if (ar0 >= N) ar0 = N - 1;
    int ar1 = ar0 + 16;        if (ar1 >= N) ar1 = N - 1;
    int ac = (l >> 4) * 8;
    short8 ah0[4], ah1[4], ag0[4], ag1[4];
#pragma unroll
    for (int s = 0; s < 4; ++s) {
        ah0[s] = *(const short8*)&h[(size_t)ar0 * HD + s * 32 + ac];
        ah1[s] = *(const short8*)&h[(size_t)ar1 * HD + s * 32 + ac];
        ag0[s] = *(const short8*)&agg[(size_t)ar0 * HD + s * 32 + ac];
        ag1[s] = *(const short8*)&agg[(size_t)ar1 * HD + s * 32 + ac];
    }
    stage_w(WsPk, Wl, threadIdx.x);
    stage_w(WnPk, Wl + 16384, threadIdx.x);
    __syncthreads();
    if (row0 >= N) return;
    int g0 = row0 + (l & 15), g1 = g0 + 16;
    int cb0 = ((l >> 4) & 3) * 4;
#pragma unroll
    for (int t = 0; t < 8; ++t) {
        floatx4 acc0 = {0.f, 0.f, 0.f, 0.f};
        floatx4 acc1 = {0.f, 0.f, 0.f, 0.f};
#pragma unroll
        for (int s = 0; s < 4; ++s) {
            short8 ws = *(const short8*)&Wl[(t * 4 + s) * 512 + l * 8];
            acc0 = __builtin_amdgcn_mfma_f32_16x16x32_bf16(ws, ah0[s], acc0, 0, 0, 0);
            acc1 = __builtin_amdgcn_mfma_f32_16x16x32_bf16(ws, ah1[s], acc1, 0, 0, 0);
        }
#pragma unroll
        for (int s = 0; s < 4; ++s) {
            short8 wn = *(const short8*)&Wl[16384 + (t * 4 + s) * 512 + l * 8];
            acc0 = __builtin_amdgcn_mfma_f32_16x16x32_bf16(wn, ag0[s], acc0, 0, 0, 0);
            acc1 = __builtin_amdgcn_mfma_f32_16x16x32_bf16(wn, ag1[s], acc1, 0, 0, 0);
        }
        int cb = t * 16 + cb0;
        float4 bv = *(const float4*)&bias[cb];
        if (F32OUT) {
            float* out = (float*)outp;
            if (g0 < N) {
                float4 v = make_float4(acc0[0] + bv.x, acc0[1] + bv.y,
                                       acc0[2] + bv.z, acc0[3] + bv.w);
                *(float4*)&out[(size_t)g0 * HD + cb] = v;
            }
            if (g1 < N) {
                float4 v = make_float4(acc1[0] + bv.x, acc1[1] + bv.y,
                                       acc1[2] + bv.z, acc1[3] + bv.w);
                *(float4*)&out[(size_t)g1 * HD + cb] = v;
            }
        } else {
            ushort_t* out = (ushort_t*)outp;
            store_bf16(out, g0, cb, acc0, bv, false, N);
            store_bf16(out, g1, cb, acc1, bv, false, N);
        }
    }
}

// ---------------------------------------------------------------- launch -----
extern "C" void kernel_launch(void* const* d_in, const int* in_sizes, int n_in,
                              void* d_out, int out_size, void* d_ws, size_t ws_size,
                              hipStream_t stream) {
    const int*   node_ids = (const int*)d_in[0];
    const int*   src      = (const int*)d_in[1];
    const int*   dst      = (const int*)d_in[2];
    const float* emb      = (const float*)d_in[3];
    const float* Wp1      = (const float*)d_in[4];
    const float* bp1      = (const float*)d_in[5];
    const float* Ws1      = (const float*)d_in[6];
    const float* Wn1      = (const float*)d_in[7];
    const float* b1       = (const float*)d_in[8];
    const float* Wp2      = (const float*)d_in[9];
    const float* bp2      = (const float*)d_in[10];
    const float* Ws2      = (const float*)d_in[11];
    const float* Wn2      = (const float*)d_in[12];
    const float* b2       = (const float*)d_in[13];
    float* out = (float*)d_out;

    const int N = in_sizes[0];
    const int E = in_sizes[1];

    char* ws = (char*)d_ws;
    int* rp = (int*)ws;
    size_t off = (((size_t)(N + 1) * 4) + 255) & ~(size_t)255;
    ushort_t* Wpk  = (ushort_t*)(ws + off);              // 6 x 128x128 bf16
    ushort_t* h0   = Wpk + 6 * 16384;
    ushort_t* h1   = h0 + (size_t)N * HD;
    ushort_t* bufM = h1 + (size_t)N * HD;
    ushort_t* bufA = bufM + (size_t)N * HD;

    const int nbR = (N + 1 + 255) / 256;
    const int nbP = 6 * 64;
    const int nb_gemm = (N + 127) / 128;                 // 4 waves x 32 rows
    const int nb_seg  = ((N + 3) / 4) * 4;               // group*4 + slice

    k_prep<<<nbR + nbP, 256, 0, stream>>>(dst, E, rp, N,
                                          Wp1, Ws1, Wn1, Wp2, Ws2, Wn2, Wpk, nbR);

    const ushort_t* Wp1k = Wpk;
    const ushort_t* Ws1k = Wpk + 16384;
    const ushort_t* Wn1k = Wpk + 2 * 16384;
    const ushort_t* Wp2k = Wpk + 3 * 16384;
    const ushort_t* Ws2k = Wpk + 4 * 16384;
    const ushort_t* Wn2k = Wpk + 5 * 16384;

    // layer 1
    k_gather_pool<<<nb_gemm, 256, 0, stream>>>(node_ids, emb, Wp1k, bp1, h0, bufM, N);
    k_segmax<<<nb_seg, 256, 0, stream>>>(bufM, src, rp, bufA, N);
    k_dual<false><<<nb_gemm, 256, 0, stream>>>(h0, bufA, Ws1k, Wn1k, b1, h1, N);
    // layer 2
    k_pool<<<nb_gemm, 256, 0, stream>>>(h1, Wp2k, bp2, bufM, N);
    k_segmax<<<nb_seg, 256, 0, stream>>>(bufM, src, rp, bufA, N);
    k_dual<true><<<nb_gemm, 256, 0, stream>>>(h1, bufA, Ws2k, Wn2k, b2, out, N);
}

// Round 10
// 221.102 us; speedup vs baseline: 1.3314x; 1.3314x over previous
//
#include <hip/hip_runtime.h>

#define HD 128

typedef __attribute__((ext_vector_type(8))) short short8;   // 8 bf16
typedef __attribute__((ext_vector_type(4))) float floatx4;  // MFMA accumulator

typedef unsigned short ushort_t;
typedef unsigned int uint_t;

// ---------------------------------------------------------------- helpers ----
__device__ __forceinline__ ushort_t f2b(float f) {          // fp32 -> bf16 RNE
    union { float f; uint_t u; } v; v.f = f;
    uint_t r = v.u + 0x7fff + ((v.u >> 16) & 1);
    return (ushort_t)(r >> 16);
}
__device__ __forceinline__ short8 cvt8(const float* __restrict__ p) {
    float4 u = *(const float4*)p, v = *(const float4*)(p + 4);
    short8 r;
    r[0] = (short)f2b(u.x); r[1] = (short)f2b(u.y); r[2] = (short)f2b(u.z); r[3] = (short)f2b(u.w);
    r[4] = (short)f2b(v.x); r[5] = (short)f2b(v.y); r[6] = (short)f2b(v.z); r[7] = (short)f2b(v.w);
    return r;
}
// packed u16 max == per-element bf16 max for NON-NEGATIVE floats (post-ReLU m)
__device__ __forceinline__ uint_t pkmax(uint_t a, uint_t b) {
    uint_t d;
    asm("v_pk_max_u16 %0, %1, %2" : "=v"(d) : "v"(a), "v"(b));
    return d;
}
__device__ __forceinline__ uint4 pkmax4(uint4 a, uint4 b) {
    uint4 d;
    d.x = pkmax(a.x, b.x); d.y = pkmax(a.y, b.y);
    d.z = pkmax(a.z, b.z); d.w = pkmax(a.w, b.w);
    return d;
}

// ------------------------------------------------------------------ prep -----
// [0,nbR): rowptr (rp[i] = lower_bound(dst,i)); rest: W-pack to frag order.
// Frag map (identical for A- and B-operand): lane&15 -> non-K dim, quad*8+j -> K.
__global__ __launch_bounds__(256) void k_prep(const int* __restrict__ dst, int E,
                                              int* __restrict__ rp, int N,
                                              const float* W0, const float* W1,
                                              const float* W2, const float* W3,
                                              const float* W4, const float* W5,
                                              ushort_t* __restrict__ Wpk, int nbR) {
    int b = blockIdx.x;
    if (b < nbR) {
        int i = b * 256 + threadIdx.x;
        if (i > N) return;
        int lo = 0, hi = E;
        while (lo < hi) {
            int mid = (lo + hi) >> 1;
            if (dst[mid] < i) lo = mid + 1; else hi = mid;
        }
        rp[i] = lo;
    } else {
        int bb = b - nbR;
        const float* Ws[6] = {W0, W1, W2, W3, W4, W5};
        int mat = bb >> 6;
        int o = ((bb & 63) << 8) + threadIdx.x;
        int j = o & 7, l = (o >> 3) & 63, s = (o >> 9) & 3, t = o >> 11;
        int k = s * 32 + ((l >> 4) & 3) * 8 + j;
        int n = t * 16 + (l & 15);
        Wpk[(size_t)mat * 16384 + o] = f2b(Ws[mat][k * HD + n]);
    }
}

// ---------------------------------------------------------- W -> LDS stage ---
__device__ __forceinline__ void stage_w(const ushort_t* __restrict__ g,
                                        ushort_t* l, int tid) {
#pragma unroll
    for (int i = 0; i < 8; ++i) {
        int off = i * 2048 + tid * 8;
        *(short8*)&l[off] = *(const short8*)&g[off];
    }
}

// --------------------------------------------------------------- epilogue ----
// D = mfma(Wfrag, hfrag): lane&15 = h-row, quad*4+reg = output col within tile.
__device__ __forceinline__ void store_bf16(ushort_t* __restrict__ m, int row,
                                           int colbase, const floatx4& acc,
                                           const float4& bv, bool relu, int N) {
    if (row >= N) return;
    float v0 = acc[0] + bv.x, v1 = acc[1] + bv.y, v2 = acc[2] + bv.z, v3 = acc[3] + bv.w;
    if (relu) { v0 = fmaxf(v0, 0.f); v1 = fmaxf(v1, 0.f); v2 = fmaxf(v2, 0.f); v3 = fmaxf(v3, 0.f); }
    uint2 o; o.x = (uint_t)f2b(v0) | ((uint_t)f2b(v1) << 16);
    o.y = (uint_t)f2b(v2) | ((uint_t)f2b(v3) << 16);
    *(uint2*)&m[(size_t)row * HD + colbase] = o;
}

// ------------------------------------------------------ gather + pool GEMM ---
// h0 = bf16(emb[ids]);  m = relu(h0 @ Wp + b).  32 rows/wave (emb-BW bound).
__global__ __launch_bounds__(256) void k_gather_pool(const int* __restrict__ ids,
                                                     const float* __restrict__ emb,
                                                     const ushort_t* __restrict__ Wpk,
                                                     const float* __restrict__ bias,
                                                     ushort_t* __restrict__ h0,
                                                     ushort_t* __restrict__ m, int N) {
    __shared__ ushort_t Wl[16384];
    int wave = blockIdx.x * 4 + (threadIdx.x >> 6);
    int row0 = wave * 32;
    int l = threadIdx.x & 63;
    int ar0 = row0 + (l & 15); if (ar0 >= N) ar0 = N - 1;
    int ar1 = ar0 + 16;        if (ar1 >= N) ar1 = N - 1;
    int ac = (l >> 4) * 8;
    int id0 = ids[ar0], id1 = ids[ar1];
    short8 a0[4], a1[4];
#pragma unroll
    for (int s = 0; s < 4; ++s) {
        a0[s] = cvt8(&emb[(size_t)id0 * HD + s * 32 + ac]);
        a1[s] = cvt8(&emb[(size_t)id1 * HD + s * 32 + ac]);
    }
    stage_w(Wpk, Wl, threadIdx.x);
    __syncthreads();
    if (row0 >= N) return;
#pragma unroll
    for (int s = 0; s < 4; ++s) {
        *(short8*)&h0[(size_t)ar0 * HD + s * 32 + ac] = a0[s];
        *(short8*)&h0[(size_t)ar1 * HD + s * 32 + ac] = a1[s];
    }
    int g0 = row0 + (l & 15), g1 = g0 + 16;
    int cb0 = ((l >> 4) & 3) * 4;
#pragma unroll
    for (int t = 0; t < 8; ++t) {
        floatx4 acc0 = {0.f, 0.f, 0.f, 0.f};
        floatx4 acc1 = {0.f, 0.f, 0.f, 0.f};
#pragma unroll
        for (int s = 0; s < 4; ++s) {
            short8 w = *(const short8*)&Wl[(t * 4 + s) * 512 + l * 8];
            acc0 = __builtin_amdgcn_mfma_f32_16x16x32_bf16(w, a0[s], acc0, 0, 0, 0);
            acc1 = __builtin_amdgcn_mfma_f32_16x16x32_bf16(w, a1[s], acc1, 0, 0, 0);
        }
        int cb = t * 16 + cb0;
        float4 bv = *(const float4*)&bias[cb];
        store_bf16(m, g0, cb, acc0, bv, true, N);
        store_bf16(m, g1, cb, acc1, bv, true, N);
    }
}

// ----------------------------------------------------------- pool GEMM only --
// 64 rows/wave: 4 row-sets share each W fragment -> MFMA-bound, not LDS-bound.
__global__ __launch_bounds__(256, 2) void k_pool(const ushort_t* __restrict__ h,
                                                 const ushort_t* __restrict__ Wpk,
                                                 const float* __restrict__ bias,
                                                 ushort_t* __restrict__ m, int N) {
    __shared__ ushort_t Wl[16384];
    int wave = blockIdx.x * 4 + (threadIdx.x >> 6);
    int row0 = wave * 64;
    int l = threadIdx.x & 63;
    int ac = (l >> 4) * 8;
    short8 a[4][4];
#pragma unroll
    for (int set = 0; set < 4; ++set) {
        int ar = row0 + (l & 15) + set * 16; if (ar >= N) ar = N - 1;
#pragma unroll
        for (int s = 0; s < 4; ++s)
            a[set][s] = *(const short8*)&h[(size_t)ar * HD + s * 32 + ac];
    }
    stage_w(Wpk, Wl, threadIdx.x);
    __syncthreads();
    if (row0 >= N) return;
    int cb0 = ((l >> 4) & 3) * 4;
#pragma unroll
    for (int t = 0; t < 8; ++t) {
        floatx4 acc[4];
#pragma unroll
        for (int set = 0; set < 4; ++set) acc[set] = (floatx4){0.f, 0.f, 0.f, 0.f};
#pragma unroll
        for (int s = 0; s < 4; ++s) {
            short8 w = *(const short8*)&Wl[(t * 4 + s) * 512 + l * 8];
#pragma unroll
            for (int set = 0; set < 4; ++set)
                acc[set] = __builtin_amdgcn_mfma_f32_16x16x32_bf16(w, a[set][s], acc[set], 0, 0, 0);
        }
        int cb = t * 16 + cb0;
        float4 bv = *(const float4*)&bias[cb];
#pragma unroll
        for (int set = 0; set < 4; ++set)
            store_bf16(m, row0 + (l & 15) + set * 16, cb, acc[set], bv, true, N);
    }
}

// ---------------------------------------------------------------- segmax -----
// One node per wave; 4 edge-slots x 16 lanes x 16B (full 256B row per slot).
// Packed u16 max (valid: m >= 0 post-ReLU). Coalesced src load + shfl dist.
__global__ __launch_bounds__(256) void k_segmax(const ushort_t* __restrict__ m,
                                                const int* __restrict__ src,
                                                const int* __restrict__ rp,
                                                ushort_t* __restrict__ agg, int N) {
    int node = blockIdx.x * 4 + (threadIdx.x >> 6);
    if (node >= N) return;
    int l = threadIdx.x & 63;
    int slot = l >> 4;                 // 0..3 edge slot
    int col8 = (l & 15) * 8;           // 8 bf16 (16 B) per lane
    int beg = rp[node], end = rp[node + 1];
    uint4 A = {0u, 0u, 0u, 0u}, C = {0u, 0u, 0u, 0u};
    for (int base = beg; base < end; base += 64) {
        int nb = end - base; if (nb > 64) nb = 64;
        int si = base + l; if (si > end - 1) si = end - 1;
        int sv = src[si];              // coalesced: 64 edge indices per wave
        for (int o = 0; o < nb; o += 16) {
            int last = nb - 1;
            int i0 = o + slot;      if (i0 > last) i0 = last;
            int i1 = o + 4 + slot;  if (i1 > last) i1 = last;
            int i2 = o + 8 + slot;  if (i2 > last) i2 = last;
            int i3 = o + 12 + slot; if (i3 > last) i3 = last;
            int s0 = __shfl(sv, i0), s1 = __shfl(sv, i1);
            int s2 = __shfl(sv, i2), s3 = __shfl(sv, i3);
            uint4 p0 = *(const uint4*)&m[(size_t)s0 * HD + col8];
            uint4 p1 = *(const uint4*)&m[(size_t)s1 * HD + col8];
            uint4 p2 = *(const uint4*)&m[(size_t)s2 * HD + col8];
            uint4 p3 = *(const uint4*)&m[(size_t)s3 * HD + col8];
            A = pkmax4(A, p0); C = pkmax4(C, p1);
            A = pkmax4(A, p2); C = pkmax4(C, p3);
        }
    }
    A = pkmax4(A, C);
#pragma unroll
    for (int d = 16; d <= 32; d <<= 1) {
        uint4 t;
        t.x = (uint_t)__shfl_xor((int)A.x, d); t.y = (uint_t)__shfl_xor((int)A.y, d);
        t.z = (uint_t)__shfl_xor((int)A.z, d); t.w = (uint_t)__shfl_xor((int)A.w, d);
        A = pkmax4(A, t);
    }
    if (slot == 0)
        *(uint4*)&agg[(size_t)node * HD + col8] = A;
}

// ----------------------------------------------------------- dual GEMM -------
// out = h @ Wself + agg @ Wneigh + b; 64 rows/wave (W frags feed 4 row-sets).
template <bool F32OUT>
__global__ __launch_bounds__(256, 2) void k_dual(const ushort_t* __restrict__ h,
                                                 const ushort_t* __restrict__ agg,
                                                 const ushort_t* __restrict__ WsPk,
                                                 const ushort_t* __restrict__ WnPk,
                                                 const float* __restrict__ bias,
                                                 void* __restrict__ outp, int N) {
    __shared__ ushort_t Wl[32768];                       // Ws | Wn
    int wave = blockIdx.x * 4 + (threadIdx.x >> 6);
    int row0 = wave * 64;
    int l = threadIdx.x & 63;
    int ac = (l >> 4) * 8;
    short8 ah[4][4], ag[4][4];
#pragma unroll
    for (int set = 0; set < 4; ++set) {
        int ar = row0 + (l & 15) + set * 16; if (ar >= N) ar = N - 1;
#pragma unroll
        for (int s = 0; s < 4; ++s) {
            ah[set][s] = *(const short8*)&h[(size_t)ar * HD + s * 32 + ac];
            ag[set][s] = *(const short8*)&agg[(size_t)ar * HD + s * 32 + ac];
        }
    }
    stage_w(WsPk, Wl, threadIdx.x);
    stage_w(WnPk, Wl + 16384, threadIdx.x);
    __syncthreads();
    if (row0 >= N) return;
    int cb0 = ((l >> 4) & 3) * 4;
#pragma unroll
    for (int t = 0; t < 8; ++t) {
        floatx4 acc[4];
#pragma unroll
        for (int set = 0; set < 4; ++set) acc[set] = (floatx4){0.f, 0.f, 0.f, 0.f};
#pragma unroll
        for (int s = 0; s < 4; ++s) {
            short8 ws = *(const short8*)&Wl[(t * 4 + s) * 512 + l * 8];
#pragma unroll
            for (int set = 0; set < 4; ++set)
                acc[set] = __builtin_amdgcn_mfma_f32_16x16x32_bf16(ws, ah[set][s], acc[set], 0, 0, 0);
        }
#pragma unroll
        for (int s = 0; s < 4; ++s) {
            short8 wn = *(const short8*)&Wl[16384 + (t * 4 + s) * 512 + l * 8];
#pragma unroll
            for (int set = 0; set < 4; ++set)
                acc[set] = __builtin_amdgcn_mfma_f32_16x16x32_bf16(wn, ag[set][s], acc[set], 0, 0, 0);
        }
        int cb = t * 16 + cb0;
        float4 bv = *(const float4*)&bias[cb];
#pragma unroll
        for (int set = 0; set < 4; ++set) {
            int g = row0 + (l & 15) + set * 16;
            if (F32OUT) {
                if (g < N) {
                    float4 v = make_float4(acc[set][0] + bv.x, acc[set][1] + bv.y,
                                           acc[set][2] + bv.z, acc[set][3] + bv.w);
                    *(float4*)&((float*)outp)[(size_t)g * HD + cb] = v;
                }
            } else {
                store_bf16((ushort_t*)outp, g, cb, acc[set], bv, false, N);
            }
        }
    }
}

// ---------------------------------------------------------------- launch -----
extern "C" void kernel_launch(void* const* d_in, const int* in_sizes, int n_in,
                              void* d_out, int out_size, void* d_ws, size_t ws_size,
                              hipStream_t stream) {
    const int*   node_ids = (const int*)d_in[0];
    const int*   src      = (const int*)d_in[1];
    const int*   dst      = (const int*)d_in[2];
    const float* emb      = (const float*)d_in[3];
    const float* Wp1      = (const float*)d_in[4];
    const float* bp1      = (const float*)d_in[5];
    const float* Ws1      = (const float*)d_in[6];
    const float* Wn1      = (const float*)d_in[7];
    const float* b1       = (const float*)d_in[8];
    const float* Wp2      = (const float*)d_in[9];
    const float* bp2      = (const float*)d_in[10];
    const float* Ws2      = (const float*)d_in[11];
    const float* Wn2      = (const float*)d_in[12];
    const float* b2       = (const float*)d_in[13];
    float* out = (float*)d_out;

    const int N = in_sizes[0];
    const int E = in_sizes[1];

    char* ws = (char*)d_ws;
    int* rp = (int*)ws;
    size_t off = (((size_t)(N + 1) * 4) + 255) & ~(size_t)255;
    ushort_t* Wpk  = (ushort_t*)(ws + off);              // 6 x 128x128 bf16
    ushort_t* h0   = Wpk + 6 * 16384;
    ushort_t* h1   = h0 + (size_t)N * HD;
    ushort_t* bufM = h1 + (size_t)N * HD;
    ushort_t* bufA = bufM + (size_t)N * HD;

    const int nbR = (N + 1 + 255) / 256;
    const int nbP = 6 * 64;
    const int nbG32 = (N + 127) / 128;                   // 4 waves x 32 rows
    const int nbG64 = (N + 255) / 256;                   // 4 waves x 64 rows
    const int nb_seg = (N + 3) / 4;                      // 1 node per wave

    k_prep<<<nbR + nbP, 256, 0, stream>>>(dst, E, rp, N,
                                          Wp1, Ws1, Wn1, Wp2, Ws2, Wn2, Wpk, nbR);

    const ushort_t* Wp1k = Wpk;
    const ushort_t* Ws1k = Wpk + 16384;
    const ushort_t* Wn1k = Wpk + 2 * 16384;
    const ushort_t* Wp2k = Wpk + 3 * 16384;
    const ushort_t* Ws2k = Wpk + 4 * 16384;
    const ushort_t* Wn2k = Wpk + 5 * 16384;

    // layer 1
    k_gather_pool<<<nbG32, 256, 0, stream>>>(node_ids, emb, Wp1k, bp1, h0, bufM, N);
    k_segmax<<<nb_seg, 256, 0, stream>>>(bufM, src, rp, bufA, N);
    k_dual<false><<<nbG64, 256, 0, stream>>>(h0, bufA, Ws1k, Wn1k, b1, h1, N);
    // layer 2
    k_pool<<<nbG64, 256, 0, stream>>>(h1, Wp2k, bp2, bufM, N);
    k_segmax<<<nb_seg, 256, 0, stream>>>(bufM, src, rp, bufA, N);
    k_dual<true><<<nbG64, 256, 0, stream>>>(h1, bufA, Ws2k, Wn2k, b2, out, N);
}

// Round 11
// 220.587 us; speedup vs baseline: 1.3345x; 1.0023x over previous
//
#include <hip/hip_runtime.h>

#define HD 128

typedef __attribute__((ext_vector_type(8))) short short8;   // 8 bf16
typedef __attribute__((ext_vector_type(4))) float floatx4;  // MFMA accumulator

typedef unsigned short ushort_t;
typedef unsigned int uint_t;

// ---------------------------------------------------------------- helpers ----
__device__ __forceinline__ ushort_t f2b(float f) {          // fp32 -> bf16 RNE
    union { float f; uint_t u; } v; v.f = f;
    uint_t r = v.u + 0x7fff + ((v.u >> 16) & 1);
    return (ushort_t)(r >> 16);
}
__device__ __forceinline__ short8 cvt8(const float* __restrict__ p) {
    float4 u = *(const float4*)p, v = *(const float4*)(p + 4);
    short8 r;
    r[0] = (short)f2b(u.x); r[1] = (short)f2b(u.y); r[2] = (short)f2b(u.z); r[3] = (short)f2b(u.w);
    r[4] = (short)f2b(v.x); r[5] = (short)f2b(v.y); r[6] = (short)f2b(v.z); r[7] = (short)f2b(v.w);
    return r;
}
// packed u16 max == per-element bf16 max for NON-NEGATIVE floats (post-ReLU m)
__device__ __forceinline__ uint_t pkmax(uint_t a, uint_t b) {
    uint_t d;
    asm("v_pk_max_u16 %0, %1, %2" : "=v"(d) : "v"(a), "v"(b));
    return d;
}
__device__ __forceinline__ uint4 pkmax4(uint4 a, uint4 b) {
    uint4 d;
    d.x = pkmax(a.x, b.x); d.y = pkmax(a.y, b.y);
    d.z = pkmax(a.z, b.z); d.w = pkmax(a.w, b.w);
    return d;
}

// ------------------------------------------------------------------ prep -----
// [0,nbR): rowptr (rp[i] = lower_bound(dst,i)); rest: W-pack to frag order.
// Frag map (identical for A- and B-operand): lane&15 -> non-K dim, quad*8+j -> K.
__global__ __launch_bounds__(256) void k_prep(const int* __restrict__ dst, int E,
                                              int* __restrict__ rp, int N,
                                              const float* W0, const float* W1,
                                              const float* W2, const float* W3,
                                              const float* W4, const float* W5,
                                              ushort_t* __restrict__ Wpk, int nbR) {
    int b = blockIdx.x;
    if (b < nbR) {
        int i = b * 256 + threadIdx.x;
        if (i > N) return;
        int lo = 0, hi = E;
        while (lo < hi) {
            int mid = (lo + hi) >> 1;
            if (dst[mid] < i) lo = mid + 1; else hi = mid;
        }
        rp[i] = lo;
    } else {
        int bb = b - nbR;
        const float* Ws[6] = {W0, W1, W2, W3, W4, W5};
        int mat = bb >> 6;
        int o = ((bb & 63) << 8) + threadIdx.x;
        int j = o & 7, l = (o >> 3) & 63, s = (o >> 9) & 3, t = o >> 11;
        int k = s * 32 + ((l >> 4) & 3) * 8 + j;
        int n = t * 16 + (l & 15);
        Wpk[(size_t)mat * 16384 + o] = f2b(Ws[mat][k * HD + n]);
    }
}

// ---------------------------------------------------------- W -> LDS stage ---
__device__ __forceinline__ void stage_w(const ushort_t* __restrict__ g,
                                        ushort_t* l, int tid) {
#pragma unroll
    for (int i = 0; i < 8; ++i) {
        int off = i * 2048 + tid * 8;
        *(short8*)&l[off] = *(const short8*)&g[off];
    }
}

// --------------------------------------------------------------- epilogue ----
// D = mfma(Wfrag, hfrag): lane&15 = h-row, quad*4+reg = output col within tile.
__device__ __forceinline__ void store_bf16(ushort_t* __restrict__ m, int row,
                                           int colbase, const floatx4& acc,
                                           const float4& bv, bool relu, int N) {
    if (row >= N) return;
    float v0 = acc[0] + bv.x, v1 = acc[1] + bv.y, v2 = acc[2] + bv.z, v3 = acc[3] + bv.w;
    if (relu) { v0 = fmaxf(v0, 0.f); v1 = fmaxf(v1, 0.f); v2 = fmaxf(v2, 0.f); v3 = fmaxf(v3, 0.f); }
    uint2 o; o.x = (uint_t)f2b(v0) | ((uint_t)f2b(v1) << 16);
    o.y = (uint_t)f2b(v2) | ((uint_t)f2b(v3) << 16);
    *(uint2*)&m[(size_t)row * HD + colbase] = o;
}

// ------------------------------------------------------------------ warm -----
// Stream a buffer sequentially so the memory-side L3 read-allocates it;
// the following segmax's random re-reads (16x reuse/line) then hit L3 instead
// of random HBM. XOR-accumulate + never-true guarded store keeps loads alive.
__global__ __launch_bounds__(256) void k_warm(const uint4* __restrict__ p, int n4,
                                              uint_t* __restrict__ sink) {
    uint_t acc = 0;
    int stride = gridDim.x * 256;
    for (int i = blockIdx.x * 256 + threadIdx.x; i < n4; i += stride) {
        uint4 v = p[i];
        acc ^= v.x ^ v.y ^ v.z ^ v.w;
    }
    if (acc == 0xDEADBEEFu) sink[blockIdx.x] = acc;   // effectively never
}

// ------------------------------------------------------ gather + pool GEMM ---
// h0 = bf16(emb[ids]);  m = relu(h0 @ Wp + b).  32 rows/wave; A overlaps stage.
__global__ __launch_bounds__(256) void k_gather_pool(const int* __restrict__ ids,
                                                     const float* __restrict__ emb,
                                                     const ushort_t* __restrict__ Wpk,
                                                     const float* __restrict__ bias,
                                                     ushort_t* __restrict__ h0,
                                                     ushort_t* __restrict__ m, int N) {
    __shared__ ushort_t Wl[16384];
    int wave = blockIdx.x * 4 + (threadIdx.x >> 6);
    int row0 = wave * 32;
    int l = threadIdx.x & 63;
    int ar0 = row0 + (l & 15); if (ar0 >= N) ar0 = N - 1;
    int ar1 = ar0 + 16;        if (ar1 >= N) ar1 = N - 1;
    int ac = (l >> 4) * 8;
    int id0 = ids[ar0], id1 = ids[ar1];
    short8 a0[4], a1[4];
#pragma unroll
    for (int s = 0; s < 4; ++s) {
        a0[s] = cvt8(&emb[(size_t)id0 * HD + s * 32 + ac]);
        a1[s] = cvt8(&emb[(size_t)id1 * HD + s * 32 + ac]);
    }
    stage_w(Wpk, Wl, threadIdx.x);
    __syncthreads();
    if (row0 >= N) return;
#pragma unroll
    for (int s = 0; s < 4; ++s) {
        *(short8*)&h0[(size_t)ar0 * HD + s * 32 + ac] = a0[s];
        *(short8*)&h0[(size_t)ar1 * HD + s * 32 + ac] = a1[s];
    }
    int g0 = row0 + (l & 15), g1 = g0 + 16;
    int cb0 = ((l >> 4) & 3) * 4;
#pragma unroll
    for (int t = 0; t < 8; ++t) {
        floatx4 acc0 = {0.f, 0.f, 0.f, 0.f};
        floatx4 acc1 = {0.f, 0.f, 0.f, 0.f};
#pragma unroll
        for (int s = 0; s < 4; ++s) {
            short8 w = *(const short8*)&Wl[(t * 4 + s) * 512 + l * 8];
            acc0 = __builtin_amdgcn_mfma_f32_16x16x32_bf16(w, a0[s], acc0, 0, 0, 0);
            acc1 = __builtin_amdgcn_mfma_f32_16x16x32_bf16(w, a1[s], acc1, 0, 0, 0);
        }
        int cb = t * 16 + cb0;
        float4 bv = *(const float4*)&bias[cb];
        store_bf16(m, g0, cb, acc0, bv, true, N);
        store_bf16(m, g1, cb, acc1, bv, true, N);
    }
}

// ----------------------------------------------------------- pool GEMM only --
__global__ __launch_bounds__(256) void k_pool(const ushort_t* __restrict__ h,
                                              const ushort_t* __restrict__ Wpk,
                                              const float* __restrict__ bias,
                                              ushort_t* __restrict__ m, int N) {
    __shared__ ushort_t Wl[16384];
    int wave = blockIdx.x * 4 + (threadIdx.x >> 6);
    int row0 = wave * 32;
    int l = threadIdx.x & 63;
    int ar0 = row0 + (l & 15); if (ar0 >= N) ar0 = N - 1;
    int ar1 = ar0 + 16;        if (ar1 >= N) ar1 = N - 1;
    int ac = (l >> 4) * 8;
    short8 a0[4], a1[4];
#pragma unroll
    for (int s = 0; s < 4; ++s) {
        a0[s] = *(const short8*)&h[(size_t)ar0 * HD + s * 32 + ac];
        a1[s] = *(const short8*)&h[(size_t)ar1 * HD + s * 32 + ac];
    }
    stage_w(Wpk, Wl, threadIdx.x);
    __syncthreads();
    if (row0 >= N) return;
    int g0 = row0 + (l & 15), g1 = g0 + 16;
    int cb0 = ((l >> 4) & 3) * 4;
#pragma unroll
    for (int t = 0; t < 8; ++t) {
        floatx4 acc0 = {0.f, 0.f, 0.f, 0.f};
        floatx4 acc1 = {0.f, 0.f, 0.f, 0.f};
#pragma unroll
        for (int s = 0; s < 4; ++s) {
            short8 w = *(const short8*)&Wl[(t * 4 + s) * 512 + l * 8];
            acc0 = __builtin_amdgcn_mfma_f32_16x16x32_bf16(w, a0[s], acc0, 0, 0, 0);
            acc1 = __builtin_amdgcn_mfma_f32_16x16x32_bf16(w, a1[s], acc1, 0, 0, 0);
        }
        int cb = t * 16 + cb0;
        float4 bv = *(const float4*)&bias[cb];
        store_bf16(m, g0, cb, acc0, bv, true, N);
        store_bf16(m, g1, cb, acc1, bv, true, N);
    }
}

// ---------------------------------------------------------------- segmax -----
// One node per wave; 4 edge-slots x 16 lanes x 16B; coalesced src load + shfl;
// packed u16 max (valid: m >= 0 post-ReLU).
__global__ __launch_bounds__(256) void k_segmax(const ushort_t* __restrict__ m,
                                                const int* __restrict__ src,
                                                const int* __restrict__ rp,
                                                ushort_t* __restrict__ agg, int N) {
    int node = blockIdx.x * 4 + (threadIdx.x >> 6);
    if (node >= N) return;
    int l = threadIdx.x & 63;
    int slot = l >> 4;                 // 0..3 edge slot
    int col8 = (l & 15) * 8;           // 8 bf16 (16 B) per lane
    int beg = rp[node], end = rp[node + 1];
    uint4 A = {0u, 0u, 0u, 0u}, C = {0u, 0u, 0u, 0u};
    for (int base = beg; base < end; base += 64) {
        int nb = end - base; if (nb > 64) nb = 64;
        int si = base + l; if (si > end - 1) si = end - 1;
        int sv = src[si];              // coalesced: 64 edge indices per wave
        for (int o = 0; o < nb; o += 16) {
            int last = nb - 1;
            int i0 = o + slot;      if (i0 > last) i0 = last;
            int i1 = o + 4 + slot;  if (i1 > last) i1 = last;
            int i2 = o + 8 + slot;  if (i2 > last) i2 = last;
            int i3 = o + 12 + slot; if (i3 > last) i3 = last;
            int s0 = __shfl(sv, i0), s1 = __shfl(sv, i1);
            int s2 = __shfl(sv, i2), s3 = __shfl(sv, i3);
            uint4 p0 = *(const uint4*)&m[(size_t)s0 * HD + col8];
            uint4 p1 = *(const uint4*)&m[(size_t)s1 * HD + col8];
            uint4 p2 = *(const uint4*)&m[(size_t)s2 * HD + col8];
            uint4 p3 = *(const uint4*)&m[(size_t)s3 * HD + col8];
            A = pkmax4(A, p0); C = pkmax4(C, p1);
            A = pkmax4(A, p2); C = pkmax4(C, p3);
        }
    }
    A = pkmax4(A, C);
#pragma unroll
    for (int d = 16; d <= 32; d <<= 1) {
        uint4 t;
        t.x = (uint_t)__shfl_xor((int)A.x, d); t.y = (uint_t)__shfl_xor((int)A.y, d);
        t.z = (uint_t)__shfl_xor((int)A.z, d); t.w = (uint_t)__shfl_xor((int)A.w, d);
        A = pkmax4(A, t);
    }
    if (slot == 0)
        *(uint4*)&agg[(size_t)node * HD + col8] = A;
}

// ----------------------------------------------------------- dual GEMM -------
// out = h @ Wself + agg @ Wneigh + b; 32 rows/wave; A/agg loads overlap stage.
template <bool F32OUT>
__global__ __launch_bounds__(256) void k_dual(const ushort_t* __restrict__ h,
                                              const ushort_t* __restrict__ agg,
                                              const ushort_t* __restrict__ WsPk,
                                              const ushort_t* __restrict__ WnPk,
                                              const float* __restrict__ bias,
                                              void* __restrict__ outp, int N) {
    __shared__ ushort_t Wl[32768];                       // Ws | Wn
    int wave = blockIdx.x * 4 + (threadIdx.x >> 6);
    int row0 = wave * 32;
    int l = threadIdx.x & 63;
    int ar0 = row0 + (l & 15); if (ar0 >= N) ar0 = N - 1;
    int ar1 = ar0 + 16;        if (ar1 >= N) ar1 = N - 1;
    int ac = (l >> 4) * 8;
    short8 ah0[4], ah1[4], ag0[4], ag1[4];
#pragma unroll
    for (int s = 0; s < 4; ++s) {
        ah0[s] = *(const short8*)&h[(size_t)ar0 * HD + s * 32 + ac];
        ah1[s] = *(const short8*)&h[(size_t)ar1 * HD + s * 32 + ac];
        ag0[s] = *(const short8*)&agg[(size_t)ar0 * HD + s * 32 + ac];
        ag1[s] = *(const short8*)&agg[(size_t)ar1 * HD + s * 32 + ac];
    }
    stage_w(WsPk, Wl, threadIdx.x);
    stage_w(WnPk, Wl + 16384, threadIdx.x);
    __syncthreads();
    if (row0 >= N) return;
    int g0 = row0 + (l & 15), g1 = g0 + 16;
    int cb0 = ((l >> 4) & 3) * 4;
#pragma unroll
    for (int t = 0; t < 8; ++t) {
        floatx4 acc0 = {0.f, 0.f, 0.f, 0.f};
        floatx4 acc1 = {0.f, 0.f, 0.f, 0.f};
#pragma unroll
        for (int s = 0; s < 4; ++s) {
            short8 ws = *(const short8*)&Wl[(t * 4 + s) * 512 + l * 8];
            acc0 = __builtin_amdgcn_mfma_f32_16x16x32_bf16(ws, ah0[s], acc0, 0, 0, 0);
            acc1 = __builtin_amdgcn_mfma_f32_16x16x32_bf16(ws, ah1[s], acc1, 0, 0, 0);
        }
#pragma unroll
        for (int s = 0; s < 4; ++s) {
            short8 wn = *(const short8*)&Wl[16384 + (t * 4 + s) * 512 + l * 8];
            acc0 = __builtin_amdgcn_mfma_f32_16x16x32_bf16(wn, ag0[s], acc0, 0, 0, 0);
            acc1 = __builtin_amdgcn_mfma_f32_16x16x32_bf16(wn, ag1[s], acc1, 0, 0, 0);
        }
        int cb = t * 16 + cb0;
        float4 bv = *(const float4*)&bias[cb];
        if (F32OUT) {
            float* out = (float*)outp;
            if (g0 < N) {
                float4 v = make_float4(acc0[0] + bv.x, acc0[1] + bv.y,
                                       acc0[2] + bv.z, acc0[3] + bv.w);
                *(float4*)&out[(size_t)g0 * HD + cb] = v;
            }
            if (g1 < N) {
                float4 v = make_float4(acc1[0] + bv.x, acc1[1] + bv.y,
                                       acc1[2] + bv.z, acc1[3] + bv.w);
                *(float4*)&out[(size_t)g1 * HD + cb] = v;
            }
        } else {
            ushort_t* out = (ushort_t*)outp;
            store_bf16(out, g0, cb, acc0, bv, false, N);
            store_bf16(out, g1, cb, acc1, bv, false, N);
        }
    }
}

// ---------------------------------------------------------------- launch -----
extern "C" void kernel_launch(void* const* d_in, const int* in_sizes, int n_in,
                              void* d_out, int out_size, void* d_ws, size_t ws_size,
                              hipStream_t stream) {
    const int*   node_ids = (const int*)d_in[0];
    const int*   src      = (const int*)d_in[1];
    const int*   dst      = (const int*)d_in[2];
    const float* emb      = (const float*)d_in[3];
    const float* Wp1      = (const float*)d_in[4];
    const float* bp1      = (const float*)d_in[5];
    const float* Ws1      = (const float*)d_in[6];
    const float* Wn1      = (const float*)d_in[7];
    const float* b1       = (const float*)d_in[8];
    const float* Wp2      = (const float*)d_in[9];
    const float* bp2      = (const float*)d_in[10];
    const float* Ws2      = (const float*)d_in[11];
    const float* Wn2      = (const float*)d_in[12];
    const float* b2       = (const float*)d_in[13];
    float* out = (float*)d_out;

    const int N = in_sizes[0];
    const int E = in_sizes[1];

    char* ws = (char*)d_ws;
    int* rp = (int*)ws;
    size_t off = (((size_t)(N + 1) * 4) + 255) & ~(size_t)255;
    ushort_t* Wpk  = (ushort_t*)(ws + off);              // 6 x 128x128 bf16
    ushort_t* h0   = Wpk + 6 * 16384;
    ushort_t* h1   = h0 + (size_t)N * HD;
    ushort_t* bufM = h1 + (size_t)N * HD;
    ushort_t* bufA = bufM + (size_t)N * HD;
    uint_t*   sink = (uint_t*)(bufA + (size_t)N * HD);   // warm-kernel sink

    const int nbR = (N + 1 + 255) / 256;
    const int nbP = 6 * 64;
    const int nbG = (N + 127) / 128;                     // 4 waves x 32 rows
    const int nb_seg = (N + 3) / 4;                      // 1 node per wave
    const int n4 = N * HD / 8;                           // uint4 count of bufM

    k_prep<<<nbR + nbP, 256, 0, stream>>>(dst, E, rp, N,
                                          Wp1, Ws1, Wn1, Wp2, Ws2, Wn2, Wpk, nbR);

    const ushort_t* Wp1k = Wpk;
    const ushort_t* Ws1k = Wpk + 16384;
    const ushort_t* Wn1k = Wpk + 2 * 16384;
    const ushort_t* Wp2k = Wpk + 3 * 16384;
    const ushort_t* Ws2k = Wpk + 4 * 16384;
    const ushort_t* Wn2k = Wpk + 5 * 16384;

    // layer 1
    k_gather_pool<<<nbG, 256, 0, stream>>>(node_ids, emb, Wp1k, bp1, h0, bufM, N);
    k_warm<<<512, 256, 0, stream>>>((const uint4*)bufM, n4, sink);
    k_segmax<<<nb_seg, 256, 0, stream>>>(bufM, src, rp, bufA, N);
    k_dual<false><<<nbG, 256, 0, stream>>>(h0, bufA, Ws1k, Wn1k, b1, h1, N);
    // layer 2
    k_pool<<<nbG, 256, 0, stream>>>(h1, Wp2k, bp2, bufM, N);
    k_warm<<<512, 256, 0, stream>>>((const uint4*)bufM, n4, sink);
    k_segmax<<<nb_seg, 256, 0, stream>>>(bufM, src, rp, bufA, N);
    k_dual<true><<<nbG, 256, 0, stream>>>(h1, bufA, Ws2k, Wn2k, b2, out, N);
}